// Round 17
// baseline (438.581 us; speedup 1.0000x reference)
//
#include <hip/hip_runtime.h>
#include <math.h>

#define NN 50000
#define EE 800000
#define OO 4
#define CC 64
#define KDD 16
#define KEYDD 128
#define CH 16  // gather window per chunk

typedef float v2f __attribute__((ext_vector_type(2)));

// Full-wave (64-lane) sum via DPP builtins (prologue only)
__device__ __forceinline__ float wave_red_sum(float v) {
  int x;
  x = __builtin_amdgcn_update_dpp(0, __float_as_int(v), 0x111, 0xf, 0xf, false);
  v += __int_as_float(x);
  x = __builtin_amdgcn_update_dpp(0, __float_as_int(v), 0x112, 0xf, 0xf, false);
  v += __int_as_float(x);
  x = __builtin_amdgcn_update_dpp(0, __float_as_int(v), 0x114, 0xf, 0xf, false);
  v += __int_as_float(x);
  x = __builtin_amdgcn_update_dpp(0, __float_as_int(v), 0x118, 0xf, 0xf, false);
  v += __int_as_float(x);
  x = __builtin_amdgcn_update_dpp(0, __float_as_int(v), 0x142, 0xa, 0xf, false);
  v += __int_as_float(x);
  x = __builtin_amdgcn_update_dpp(0, __float_as_int(v), 0x143, 0xc, 0xf, false);
  v += __int_as_float(x);
  return __int_as_float(__builtin_amdgcn_readlane(__float_as_int(v), 63));
}

// bare v_exp_f32: D = 2^x  (softmax runs in log2 domain)
__device__ __forceinline__ float exp2_fast(float x) {
  float r;
  asm("v_exp_f32 %0, %1" : "=v"(r) : "v"(x));
  return r;
}

// Batched reduction of FOUR 64-lane vectors -> four wave-uniform sums.
// permlane32_swap folds pairs; one asm block of 10 v_add_f32_dpp with the two
// independent chains interleaved (covers DPP wait-states). Totals at lanes 31/63.
__device__ __forceinline__ void red4(float q0, float q1, float q2, float q3,
                                     float& p0, float& p1, float& p2, float& p3) {
  asm("s_nop 1\n\tv_permlane32_swap_b32 %0, %1" : "+v"(q0), "+v"(q1));
  float ra = q0 + q1;
  asm("s_nop 1\n\tv_permlane32_swap_b32 %0, %1" : "+v"(q2), "+v"(q3));
  float rb = q2 + q3;
  asm("s_nop 1\n\t"
      "v_add_f32_dpp %0, %0, %0 row_shr:1 row_mask:0xf bank_mask:0xf bound_ctrl:0\n\t"
      "v_add_f32_dpp %1, %1, %1 row_shr:1 row_mask:0xf bank_mask:0xf bound_ctrl:0\n\t"
      "v_add_f32_dpp %0, %0, %0 row_shr:2 row_mask:0xf bank_mask:0xf bound_ctrl:0\n\t"
      "v_add_f32_dpp %1, %1, %1 row_shr:2 row_mask:0xf bank_mask:0xf bound_ctrl:0\n\t"
      "v_add_f32_dpp %0, %0, %0 row_shr:4 row_mask:0xf bank_mask:0xf bound_ctrl:0\n\t"
      "v_add_f32_dpp %1, %1, %1 row_shr:4 row_mask:0xf bank_mask:0xf bound_ctrl:0\n\t"
      "v_add_f32_dpp %0, %0, %0 row_shr:8 row_mask:0xf bank_mask:0xf bound_ctrl:0\n\t"
      "v_add_f32_dpp %1, %1, %1 row_shr:8 row_mask:0xf bank_mask:0xf bound_ctrl:0\n\t"
      "v_add_f32_dpp %0, %0, %0 row_bcast:15 row_mask:0xa bank_mask:0xf bound_ctrl:0\n\t"
      "v_add_f32_dpp %1, %1, %1 row_bcast:15 row_mask:0xa bank_mask:0xf bound_ctrl:0\n\t"
      "s_nop 0"
      : "+v"(ra), "+v"(rb));
  p0 = __int_as_float(__builtin_amdgcn_readlane(__float_as_int(ra), 31));
  p1 = __int_as_float(__builtin_amdgcn_readlane(__float_as_int(ra), 63));
  p2 = __int_as_float(__builtin_amdgcn_readlane(__float_as_int(rb), 31));
  p3 = __int_as_float(__builtin_amdgcn_readlane(__float_as_int(rb), 63));
}

// P0 (blocks 0..15): Mt[c2*64+c1] = sum_k keyW[k,c1]*qryW[k,c2] (transposed).
// Block 16: aVec/bVec/c0/fk (fk pre-scaled by 0.25).
__global__ void prep_kernel(const float* __restrict__ keyW, const float* __restrict__ keyB,
                            const float* __restrict__ qryW, const float* __restrict__ qryB,
                            const float* __restrict__ fkb, const float* __restrict__ fkw,
                            float* __restrict__ Mt, float* __restrict__ aVec,
                            float* __restrict__ bVec, float* __restrict__ c0,
                            float* __restrict__ fk) {
  __shared__ float qw[KEYDD * CC];   // 32 KB
  __shared__ float kws[KEYDD * 4];   // 2 KB
  int t = threadIdx.x, b = blockIdx.x;
  if (b < 16) {
    for (int i = t; i < KEYDD * CC; i += 256) qw[i] = qryW[i];
    for (int i = t; i < KEYDD * 4; i += 256) {
      int k = i >> 2, c1l = i & 3;
      kws[i] = keyW[k * CC + b * 4 + c1l];
    }
    __syncthreads();
    int c1l = t >> 6, c2 = t & 63;
    float s = 0.f;
    #pragma unroll 8
    for (int k = 0; k < KEYDD; ++k)
      s = fmaf(kws[k * 4 + c1l], qw[k * CC + c2], s);
    Mt[c2 * CC + b * 4 + c1l] = s;
  } else {
    if (t < CC) {
      float sa = 0.f, sb = 0.f;
      for (int k = 0; k < KEYDD; ++k) {
        sa = fmaf(keyB[k], qryW[k * CC + t], sa);
        sb = fmaf(qryB[k], keyW[k * CC + t], sb);
      }
      aVec[t] = sa; bVec[t] = sb;
    }
    if (t == 0) {
      float s = 0.f;
      for (int k = 0; k < KEYDD; ++k) s = fmaf(keyB[k], qryB[k], s);
      c0[0] = s;
    }
    for (int idx = t; idx < OO * OO * CC; idx += 256) {
      int p = idx >> 8, rem = idx & 255;
      int o = rem >> 6, c = rem & 63;
      float s = 0.f;
      #pragma unroll
      for (int kd = 0; kd < KDD; ++kd)
        s = fmaf(fkb[(p * OO + o) * KDD + kd], fkw[c * KDD + kd], s);
      fk[idx] = 0.25f * s;  // fold the 1/O normalization here
    }
  }
}

// K2a: CSR degree counts
__global__ void count_kernel(const int* __restrict__ ei, int* __restrict__ counts) {
  int e = blockIdx.x * 256 + threadIdx.x;
  if (e < EE) atomicAdd(&counts[ei[EE + e]], 1);
}

// K2b: 3-dispatch parallel exclusive scan over counts[NN] -> offsets[NN+1]
__global__ void scan1_kernel(const int* __restrict__ counts, int* __restrict__ incl,
                             int* __restrict__ bsum, int n) {
  __shared__ int buf[256];
  int t = threadIdx.x;
  int i = blockIdx.x * 256 + t;
  int v = (i < n) ? counts[i] : 0;
  buf[t] = v;
  __syncthreads();
  for (int off = 1; off < 256; off <<= 1) {
    int a = buf[t];
    int b2 = (t >= off) ? buf[t - off] : 0;
    __syncthreads();
    buf[t] = a + b2;
    __syncthreads();
  }
  if (i < n) incl[i] = buf[t];
  if (t == 255) bsum[blockIdx.x] = buf[255];
}
__global__ void scan2_kernel(const int* __restrict__ bsum, int* __restrict__ bbase, int nb) {
  __shared__ int buf[256];
  int t = threadIdx.x;
  int v = (t < nb) ? bsum[t] : 0;
  buf[t] = v;
  __syncthreads();
  for (int off = 1; off < 256; off <<= 1) {
    int a = buf[t];
    int b2 = (t >= off) ? buf[t - off] : 0;
    __syncthreads();
    buf[t] = a + b2;
    __syncthreads();
  }
  if (t < nb) bbase[t] = buf[t] - v;  // exclusive
}
__global__ void scan3_kernel(const int* __restrict__ counts, const int* __restrict__ incl,
                             const int* __restrict__ bbase, int* __restrict__ offsets, int n) {
  int i = blockIdx.x * 256 + threadIdx.x;
  if (i < n) {
    int oi = bbase[blockIdx.x] + incl[i];
    offsets[i] = oi - counts[i];
    if (i == n - 1) offsets[n] = oi;
  }
}

// K2c: fill CSR as packed (src<<32 | eid) pairs; reuses counts as cursor.
__global__ void fill_kernel(const int* __restrict__ ei, const int* __restrict__ offsets,
                            int* __restrict__ counts, long long* __restrict__ pairs) {
  int e = blockIdx.x * 256 + threadIdx.x;
  if (e < EE) {
    int d = ei[EE + e];
    int r = atomicSub(&counts[d], 1) - 1;
    int pos = offsets[d] + r;
    pairs[pos] = ((long long)ei[e] << 32) | (unsigned)e;
  }
}

// kv = dot16(kb[ej, o, :], kW[c, :]) via PACKED f32 math: 8 v_pk_fma_f32
// + 1 pk_add + 1 add. ej is an SGPR -> wave-uniform s_load path.
__device__ __forceinline__ float kv_dot(const float* __restrict__ kb, int ej, int obase,
                                        float4 kw0, float4 kw1, float4 kw2, float4 kw3) {
  const float4* bp = reinterpret_cast<const float4*>(kb + ej * (OO * KDD) + obase);
  float4 b0 = bp[0], b1 = bp[1], b2 = bp[2], b3 = bp[3];
  v2f a0 = {0.f, 0.f}, a1 = {0.f, 0.f};
  #define P2(f4, i) (reinterpret_cast<const v2f*>(&(f4))[i])
  a0 = __builtin_elementwise_fma(P2(b0, 0), P2(kw0, 0), a0);
  a1 = __builtin_elementwise_fma(P2(b0, 1), P2(kw0, 1), a1);
  a0 = __builtin_elementwise_fma(P2(b1, 0), P2(kw1, 0), a0);
  a1 = __builtin_elementwise_fma(P2(b1, 1), P2(kw1, 1), a1);
  a0 = __builtin_elementwise_fma(P2(b2, 0), P2(kw2, 0), a0);
  a1 = __builtin_elementwise_fma(P2(b2, 1), P2(kw2, 1), a1);
  a0 = __builtin_elementwise_fma(P2(b3, 0), P2(kw3, 0), a0);
  a1 = __builtin_elementwise_fma(P2(b3, 1), P2(kw3, 1), a1);
  #undef P2
  v2f s = a0 + a1;
  return s.x + s.y;
}

// K3: MEGA — R14 frame restored (best measured: 368us mega / 407.5 total).
// History of the ~46% stall investigation (all refuted):
//   R13 forced gather batch -> null (TLP already hides x-gather latency)
//   R15 cross-chunk reg pipeline -> spill (2.2GB scratch, 4x regress)
//   R16 kb via LDS DMA -> null (per-chunk barrier re-couples waves, occ 44%)
// This round: R14 + hoist the 16 e_v readlanes into an SGPR array right after
// the drain, before any compute, so all 16 kb s_loads can issue at chunk top
// and their latency overlaps red4/exp of earlier sub-blocks. Zero other change.
// launch_bounds(256,4): VGPR cap 128 — room for the batch, no spill (R4 NOTE:
// (256,8) capped VGPR at 64 -> spilled -> 4x regress).
__global__ __launch_bounds__(256, 4) void mega_kernel(
    const float* __restrict__ x, const float* __restrict__ Mt,
    const float* __restrict__ aVec, const float* __restrict__ bVec,
    const float* __restrict__ c0p, const float* __restrict__ kb,
    const float* __restrict__ kW, const int* __restrict__ offsets,
    const long long* __restrict__ pairs, const float* __restrict__ fkg,
    const float* __restrict__ bias, float* __restrict__ out) {
  __shared__ float x1[OO * CC];
  int n = blockIdx.x;
  int t = threadIdx.x;
  int o = __builtin_amdgcn_readfirstlane(t >> 6);
  int c = t & 63;
  const float scale2 = 0.12751541050862828f;  // (1/sqrt(128)) * log2(e)
  int js = offsets[n], je = offsets[n + 1];
  int deg = je - js;

  int lane16 = c & 15;
  long long pr = 0;
  if (deg > 0) pr = pairs[js + min(lane16, deg - 1)];  // chunk-0 head, in flight early

  // ub = (Mt^T xrow + bVec) * scale2 — scalar-pipe xrow, 4 split chains
  int rowoff = __builtin_amdgcn_readfirstlane((n * OO + o) * CC);
  const float* xrow = x + rowoff;
  float ub0 = 0.f, ub1 = 0.f, ub2 = 0.f, ub3 = 0.f;
  #pragma unroll
  for (int q = 0; q < 16; ++q) {
    ub0 = fmaf(Mt[(4 * q + 0) * CC + c], xrow[4 * q + 0], ub0);
    ub1 = fmaf(Mt[(4 * q + 1) * CC + c], xrow[4 * q + 1], ub1);
    ub2 = fmaf(Mt[(4 * q + 2) * CC + c], xrow[4 * q + 2], ub2);
    ub3 = fmaf(Mt[(4 * q + 3) * CC + c], xrow[4 * q + 3], ub3);
  }
  float ubr = (((ub0 + ub1) + (ub2 + ub3)) + bVec[c]) * scale2;
  float xown = xrow[c];  // per-lane read of own row (vector load)
  float base2 = (wave_red_sum(aVec[c] * xown) + c0p[0]) * scale2;

  const float4* kwp = reinterpret_cast<const float4*>(kW + c * KDD);
  float4 kw0 = kwp[0], kw1 = kwp[1], kw2 = kwp[2], kw3 = kwp[3];
  int obase = o * KDD;
  int voff = c << 2;  // per-lane byte offset into a row

  float S = 0.f, acc = 0.f;

  for (int cs = 0; cs < deg; cs += CH) {
    int cl = deg - cs; if (cl > CH) cl = CH;  // wave-uniform
    int e_v = (int)((unsigned long long)pr & 0xffffffffu);
    int s_v = (int)(pr >> 32);
    float xv[CH];
    // 1) FORCED 16-wide gather batch: volatile asm, scalar row base + v-offset.
    #pragma unroll
    for (int j = 0; j < CH; ++j) {
      int sj = __builtin_amdgcn_readlane(s_v, j);         // SGPR row id
      const float* pj = x + (size_t)(sj * OO + o) * CC;   // scalar address math
      asm volatile("global_load_dword %0, %1, %2"
                   : "=v"(xv[j]) : "v"(voff), "s"(pj));
    }
    asm volatile("s_waitcnt vmcnt(0)" ::: "memory");
    __builtin_amdgcn_sched_barrier(0);  // consumers must not hoist above the drain
    // 2) prefetch next chunk's pairs (in flight across the compute phase)
    int ns = cs + CH;
    if (ns < deg) {
      int ncl = deg - ns;
      pr = pairs[js + ns + min(lane16, ncl - 1)];
    }
    // 2b) hoist ALL edge-id readlanes now (SGPR-destined) so every kb s_load
    //     can issue at chunk top; latency overlaps earlier sub-blocks' VALU.
    int es[CH];
    #pragma unroll
    for (int j = 0; j < CH; ++j) es[j] = __builtin_amdgcn_readlane(e_v, j);
    __builtin_amdgcn_sched_barrier(0);  // pin prefetch + id extraction before compute
    // 3) compute in 4-edge sub-blocks — no max/rescale chain, direct exp2
    #define SUB4(J0)                                                           \
    {                                                                          \
      float kv0 = kv_dot(kb, es[(J0) + 0], obase, kw0, kw1, kw2, kw3);         \
      float kv1 = kv_dot(kb, es[(J0) + 1], obase, kw0, kw1, kw2, kw3);         \
      float kv2 = kv_dot(kb, es[(J0) + 2], obase, kw0, kw1, kw2, kw3);         \
      float kv3 = kv_dot(kb, es[(J0) + 3], obase, kw0, kw1, kw2, kw3);         \
      float p0, p1, p2, p3;                                                    \
      red4(xv[(J0) + 0] * ubr, xv[(J0) + 1] * ubr,                             \
           xv[(J0) + 2] * ubr, xv[(J0) + 3] * ubr, p0, p1, p2, p3);            \
      float ev0 = ((J0) + 0 < cl) ? exp2_fast(p0) : 0.f;                       \
      float ev1 = ((J0) + 1 < cl) ? exp2_fast(p1) : 0.f;                       \
      float ev2 = ((J0) + 2 < cl) ? exp2_fast(p2) : 0.f;                       \
      float ev3 = ((J0) + 3 < cl) ? exp2_fast(p3) : 0.f;                       \
      S += (ev0 + ev1) + (ev2 + ev3);                                          \
      acc = fmaf(ev0 * kv0, xv[(J0) + 0], acc);                                \
      acc = fmaf(ev1 * kv1, xv[(J0) + 1], acc);                                \
      acc = fmaf(ev2 * kv2, xv[(J0) + 2], acc);                                \
      acc = fmaf(ev3 * kv3, xv[(J0) + 3], acc);                                \
    }
    SUB4(0)
    if (cl > 4)  SUB4(4)
    if (cl > 8)  SUB4(8)
    if (cl > 12) SUB4(12)
    #undef SUB4
  }

  // epsilon restored in the unshifted-logit domain: denom = S + 1e-6*2^(-base2)
  float invd = 1.0f / (S + 1e-6f * exp2_fast(-base2));
  x1[t] = acc * invd;
  __syncthreads();
  // fiber mix: out[n,p=o,c] = sum_oo x1[oo,c]*fk[o,oo,c] + bias[c]  (0.25 in fk)
  float s2s = 0.f;
  #pragma unroll
  for (int oo = 0; oo < OO; ++oo)
    s2s = fmaf(x1[oo * CC + c], fkg[o * (OO * CC) + oo * CC + c], s2s);
  out[(size_t)n * (OO * CC) + t] = s2s + bias[c];
}

extern "C" void kernel_launch(void* const* d_in, const int* in_sizes, int n_in,
                              void* d_out, int out_size, void* d_ws, size_t ws_size,
                              hipStream_t stream) {
  const float* x    = (const float*)d_in[0];
  const float* kb   = (const float*)d_in[1];
  const float* fkb  = (const float*)d_in[2];
  const int*   ei   = (const int*)d_in[3];
  const float* kW   = (const float*)d_in[4];
  const float* fkW  = (const float*)d_in[5];
  const float* keyW = (const float*)d_in[6];
  const float* keyB = (const float*)d_in[7];
  const float* qryW = (const float*)d_in[8];
  const float* qryB = (const float*)d_in[9];
  const float* bias = (const float*)d_in[10];
  float* out = (float*)d_out;

  const int NB = (NN + 255) / 256;  // 196 scan blocks

  float* wsf  = (float*)d_ws;
  float* Mt   = wsf;                          // 4096
  float* aVec = Mt + 4096;                    // 64
  float* bVec = aVec + 64;                    // 64
  float* c0   = bVec + 64;                    // 1 (+63 pad)
  float* fk   = c0 + 64;                      // 1024
  long long* pairs = (long long*)(fk + 1024); // EE * 8B (8B-aligned: 5312 floats before)
  int* counts    = (int*)(pairs + EE);        // 50000
  int* offsets   = counts + NN;               // 50001
  int* incl      = offsets + NN + 1;          // 50000
  int* bsum      = incl + NN;                 // NB
  int* bbase     = bsum + 256;                // NB

  hipMemsetAsync(counts, 0, (size_t)NN * sizeof(int), stream);

  prep_kernel<<<17, 256, 0, stream>>>(keyW, keyB, qryW, qryB, fkb, fkW, Mt, aVec, bVec, c0, fk);
  count_kernel<<<(EE + 255) / 256, 256, 0, stream>>>(ei, counts);
  scan1_kernel<<<NB, 256, 0, stream>>>(counts, incl, bsum, NN);
  scan2_kernel<<<1, 256, 0, stream>>>(bsum, bbase, NB);
  scan3_kernel<<<NB, 256, 0, stream>>>(counts, incl, bbase, offsets, NN);
  fill_kernel<<<(EE + 255) / 256, 256, 0, stream>>>(ei, offsets, counts, pairs);
  mega_kernel<<<NN, 256, 0, stream>>>(x, Mt, aVec, bVec, c0, kb, kW, offsets, pairs,
                                      fk, bias, out);
}

// Round 18
// 407.447 us; speedup vs baseline: 1.0764x; 1.0764x over previous
//
#include <hip/hip_runtime.h>
#include <math.h>

#define NN 50000
#define EE 800000
#define OO 4
#define CC 64
#define KDD 16
#define KEYDD 128
#define CH 16  // gather window per chunk

typedef float v2f __attribute__((ext_vector_type(2)));

// Full-wave (64-lane) sum via DPP builtins (prologue only)
__device__ __forceinline__ float wave_red_sum(float v) {
  int x;
  x = __builtin_amdgcn_update_dpp(0, __float_as_int(v), 0x111, 0xf, 0xf, false);
  v += __int_as_float(x);
  x = __builtin_amdgcn_update_dpp(0, __float_as_int(v), 0x112, 0xf, 0xf, false);
  v += __int_as_float(x);
  x = __builtin_amdgcn_update_dpp(0, __float_as_int(v), 0x114, 0xf, 0xf, false);
  v += __int_as_float(x);
  x = __builtin_amdgcn_update_dpp(0, __float_as_int(v), 0x118, 0xf, 0xf, false);
  v += __int_as_float(x);
  x = __builtin_amdgcn_update_dpp(0, __float_as_int(v), 0x142, 0xa, 0xf, false);
  v += __int_as_float(x);
  x = __builtin_amdgcn_update_dpp(0, __float_as_int(v), 0x143, 0xc, 0xf, false);
  v += __int_as_float(x);
  return __int_as_float(__builtin_amdgcn_readlane(__float_as_int(v), 63));
}

// bare v_exp_f32: D = 2^x  (softmax runs in log2 domain)
__device__ __forceinline__ float exp2_fast(float x) {
  float r;
  asm("v_exp_f32 %0, %1" : "=v"(r) : "v"(x));
  return r;
}

// Batched reduction of FOUR 64-lane vectors -> four wave-uniform sums.
// permlane32_swap folds pairs; one asm block of 10 v_add_f32_dpp with the two
// independent chains interleaved (covers DPP wait-states). Totals at lanes 31/63.
__device__ __forceinline__ void red4(float q0, float q1, float q2, float q3,
                                     float& p0, float& p1, float& p2, float& p3) {
  asm("s_nop 1\n\tv_permlane32_swap_b32 %0, %1" : "+v"(q0), "+v"(q1));
  float ra = q0 + q1;
  asm("s_nop 1\n\tv_permlane32_swap_b32 %0, %1" : "+v"(q2), "+v"(q3));
  float rb = q2 + q3;
  asm("s_nop 1\n\t"
      "v_add_f32_dpp %0, %0, %0 row_shr:1 row_mask:0xf bank_mask:0xf bound_ctrl:0\n\t"
      "v_add_f32_dpp %1, %1, %1 row_shr:1 row_mask:0xf bank_mask:0xf bound_ctrl:0\n\t"
      "v_add_f32_dpp %0, %0, %0 row_shr:2 row_mask:0xf bank_mask:0xf bound_ctrl:0\n\t"
      "v_add_f32_dpp %1, %1, %1 row_shr:2 row_mask:0xf bank_mask:0xf bound_ctrl:0\n\t"
      "v_add_f32_dpp %0, %0, %0 row_shr:4 row_mask:0xf bank_mask:0xf bound_ctrl:0\n\t"
      "v_add_f32_dpp %1, %1, %1 row_shr:4 row_mask:0xf bank_mask:0xf bound_ctrl:0\n\t"
      "v_add_f32_dpp %0, %0, %0 row_shr:8 row_mask:0xf bank_mask:0xf bound_ctrl:0\n\t"
      "v_add_f32_dpp %1, %1, %1 row_shr:8 row_mask:0xf bank_mask:0xf bound_ctrl:0\n\t"
      "v_add_f32_dpp %0, %0, %0 row_bcast:15 row_mask:0xa bank_mask:0xf bound_ctrl:0\n\t"
      "v_add_f32_dpp %1, %1, %1 row_bcast:15 row_mask:0xa bank_mask:0xf bound_ctrl:0\n\t"
      "s_nop 0"
      : "+v"(ra), "+v"(rb));
  p0 = __int_as_float(__builtin_amdgcn_readlane(__float_as_int(ra), 31));
  p1 = __int_as_float(__builtin_amdgcn_readlane(__float_as_int(ra), 63));
  p2 = __int_as_float(__builtin_amdgcn_readlane(__float_as_int(rb), 31));
  p3 = __int_as_float(__builtin_amdgcn_readlane(__float_as_int(rb), 63));
}

// P0 (blocks 0..15): Mt[c2*64+c1] = sum_k keyW[k,c1]*qryW[k,c2] (transposed).
// Block 16: aVec/bVec/c0/fk (fk pre-scaled by 0.25).
__global__ void prep_kernel(const float* __restrict__ keyW, const float* __restrict__ keyB,
                            const float* __restrict__ qryW, const float* __restrict__ qryB,
                            const float* __restrict__ fkb, const float* __restrict__ fkw,
                            float* __restrict__ Mt, float* __restrict__ aVec,
                            float* __restrict__ bVec, float* __restrict__ c0,
                            float* __restrict__ fk) {
  __shared__ float qw[KEYDD * CC];   // 32 KB
  __shared__ float kws[KEYDD * 4];   // 2 KB
  int t = threadIdx.x, b = blockIdx.x;
  if (b < 16) {
    for (int i = t; i < KEYDD * CC; i += 256) qw[i] = qryW[i];
    for (int i = t; i < KEYDD * 4; i += 256) {
      int k = i >> 2, c1l = i & 3;
      kws[i] = keyW[k * CC + b * 4 + c1l];
    }
    __syncthreads();
    int c1l = t >> 6, c2 = t & 63;
    float s = 0.f;
    #pragma unroll 8
    for (int k = 0; k < KEYDD; ++k)
      s = fmaf(kws[k * 4 + c1l], qw[k * CC + c2], s);
    Mt[c2 * CC + b * 4 + c1l] = s;
  } else {
    if (t < CC) {
      float sa = 0.f, sb = 0.f;
      for (int k = 0; k < KEYDD; ++k) {
        sa = fmaf(keyB[k], qryW[k * CC + t], sa);
        sb = fmaf(qryB[k], keyW[k * CC + t], sb);
      }
      aVec[t] = sa; bVec[t] = sb;
    }
    if (t == 0) {
      float s = 0.f;
      for (int k = 0; k < KEYDD; ++k) s = fmaf(keyB[k], qryB[k], s);
      c0[0] = s;
    }
    for (int idx = t; idx < OO * OO * CC; idx += 256) {
      int p = idx >> 8, rem = idx & 255;
      int o = rem >> 6, c = rem & 63;
      float s = 0.f;
      #pragma unroll
      for (int kd = 0; kd < KDD; ++kd)
        s = fmaf(fkb[(p * OO + o) * KDD + kd], fkw[c * KDD + kd], s);
      fk[idx] = 0.25f * s;  // fold the 1/O normalization here
    }
  }
}

// K2a: CSR degree counts
__global__ void count_kernel(const int* __restrict__ ei, int* __restrict__ counts) {
  int e = blockIdx.x * 256 + threadIdx.x;
  if (e < EE) atomicAdd(&counts[ei[EE + e]], 1);
}

// K2b: 3-dispatch parallel exclusive scan over counts[NN] -> offsets[NN+1]
__global__ void scan1_kernel(const int* __restrict__ counts, int* __restrict__ incl,
                             int* __restrict__ bsum, int n) {
  __shared__ int buf[256];
  int t = threadIdx.x;
  int i = blockIdx.x * 256 + t;
  int v = (i < n) ? counts[i] : 0;
  buf[t] = v;
  __syncthreads();
  for (int off = 1; off < 256; off <<= 1) {
    int a = buf[t];
    int b2 = (t >= off) ? buf[t - off] : 0;
    __syncthreads();
    buf[t] = a + b2;
    __syncthreads();
  }
  if (i < n) incl[i] = buf[t];
  if (t == 255) bsum[blockIdx.x] = buf[255];
}
__global__ void scan2_kernel(const int* __restrict__ bsum, int* __restrict__ bbase, int nb) {
  __shared__ int buf[256];
  int t = threadIdx.x;
  int v = (t < nb) ? bsum[t] : 0;
  buf[t] = v;
  __syncthreads();
  for (int off = 1; off < 256; off <<= 1) {
    int a = buf[t];
    int b2 = (t >= off) ? buf[t - off] : 0;
    __syncthreads();
    buf[t] = a + b2;
    __syncthreads();
  }
  if (t < nb) bbase[t] = buf[t] - v;  // exclusive
}
__global__ void scan3_kernel(const int* __restrict__ counts, const int* __restrict__ incl,
                             const int* __restrict__ bbase, int* __restrict__ offsets, int n) {
  int i = blockIdx.x * 256 + threadIdx.x;
  if (i < n) {
    int oi = bbase[blockIdx.x] + incl[i];
    offsets[i] = oi - counts[i];
    if (i == n - 1) offsets[n] = oi;
  }
}

// K2c: fill CSR as packed (src<<32 | eid) pairs; reuses counts as cursor.
__global__ void fill_kernel(const int* __restrict__ ei, const int* __restrict__ offsets,
                            int* __restrict__ counts, long long* __restrict__ pairs) {
  int e = blockIdx.x * 256 + threadIdx.x;
  if (e < EE) {
    int d = ei[EE + e];
    int r = atomicSub(&counts[d], 1) - 1;
    int pos = offsets[d] + r;
    pairs[pos] = ((long long)ei[e] << 32) | (unsigned)e;
  }
}

// kv = dot16(kb[ej, o, :], kW[c, :]) via PACKED f32 math: 8 v_pk_fma_f32
// + 1 pk_add + 1 add. ej is an SGPR -> wave-uniform s_load path.
__device__ __forceinline__ float kv_dot(const float* __restrict__ kb, int ej, int obase,
                                        float4 kw0, float4 kw1, float4 kw2, float4 kw3) {
  const float4* bp = reinterpret_cast<const float4*>(kb + ej * (OO * KDD) + obase);
  float4 b0 = bp[0], b1 = bp[1], b2 = bp[2], b3 = bp[3];
  v2f a0 = {0.f, 0.f}, a1 = {0.f, 0.f};
  #define P2(f4, i) (reinterpret_cast<const v2f*>(&(f4))[i])
  a0 = __builtin_elementwise_fma(P2(b0, 0), P2(kw0, 0), a0);
  a1 = __builtin_elementwise_fma(P2(b0, 1), P2(kw0, 1), a1);
  a0 = __builtin_elementwise_fma(P2(b1, 0), P2(kw1, 0), a0);
  a1 = __builtin_elementwise_fma(P2(b1, 1), P2(kw1, 1), a1);
  a0 = __builtin_elementwise_fma(P2(b2, 0), P2(kw2, 0), a0);
  a1 = __builtin_elementwise_fma(P2(b2, 1), P2(kw2, 1), a1);
  a0 = __builtin_elementwise_fma(P2(b3, 0), P2(kw3, 0), a0);
  a1 = __builtin_elementwise_fma(P2(b3, 1), P2(kw3, 1), a1);
  #undef P2
  v2f s = a0 + a1;
  return s.x + s.y;
}

// K3: MEGA — R14 configuration, byte-identical restore (best measured:
// mega 368us / total 407.5us). Stall-hypothesis experiment table (all refuted):
//   R13 forced gather batch   -> null  (TLP already hides x-gather latency)
//   R15 cross-chunk reg pipe  -> spill (2.2GB scratch, 4x regress)
//   R16 kb via LDS DMA        -> null  (per-chunk barrier re-couples waves)
//   R17 readlane hoist        -> -8%   (serialized SGPR extraction at chunk top)
// Structure: forced-asm 16-wide x-gather batch (codegen-stable), scalar-pipe
// ub prologue (no LDS/barrier), no-max softmax in log2 domain with the 1e-6
// epsilon restored once at the end. launch_bounds(256,4): VGPR cap 128.
__global__ __launch_bounds__(256, 4) void mega_kernel(
    const float* __restrict__ x, const float* __restrict__ Mt,
    const float* __restrict__ aVec, const float* __restrict__ bVec,
    const float* __restrict__ c0p, const float* __restrict__ kb,
    const float* __restrict__ kW, const int* __restrict__ offsets,
    const long long* __restrict__ pairs, const float* __restrict__ fkg,
    const float* __restrict__ bias, float* __restrict__ out) {
  __shared__ float x1[OO * CC];
  int n = blockIdx.x;
  int t = threadIdx.x;
  int o = __builtin_amdgcn_readfirstlane(t >> 6);
  int c = t & 63;
  const float scale2 = 0.12751541050862828f;  // (1/sqrt(128)) * log2(e)
  int js = offsets[n], je = offsets[n + 1];
  int deg = je - js;

  int lane16 = c & 15;
  long long pr = 0;
  if (deg > 0) pr = pairs[js + min(lane16, deg - 1)];  // chunk-0 head, in flight early

  // ub = (Mt^T xrow + bVec) * scale2 — scalar-pipe xrow, 4 split chains
  int rowoff = __builtin_amdgcn_readfirstlane((n * OO + o) * CC);
  const float* xrow = x + rowoff;
  float ub0 = 0.f, ub1 = 0.f, ub2 = 0.f, ub3 = 0.f;
  #pragma unroll
  for (int q = 0; q < 16; ++q) {
    ub0 = fmaf(Mt[(4 * q + 0) * CC + c], xrow[4 * q + 0], ub0);
    ub1 = fmaf(Mt[(4 * q + 1) * CC + c], xrow[4 * q + 1], ub1);
    ub2 = fmaf(Mt[(4 * q + 2) * CC + c], xrow[4 * q + 2], ub2);
    ub3 = fmaf(Mt[(4 * q + 3) * CC + c], xrow[4 * q + 3], ub3);
  }
  float ubr = (((ub0 + ub1) + (ub2 + ub3)) + bVec[c]) * scale2;
  float xown = xrow[c];  // per-lane read of own row (vector load)
  float base2 = (wave_red_sum(aVec[c] * xown) + c0p[0]) * scale2;

  const float4* kwp = reinterpret_cast<const float4*>(kW + c * KDD);
  float4 kw0 = kwp[0], kw1 = kwp[1], kw2 = kwp[2], kw3 = kwp[3];
  int obase = o * KDD;
  int voff = c << 2;  // per-lane byte offset into a row

  float S = 0.f, acc = 0.f;

  for (int cs = 0; cs < deg; cs += CH) {
    int cl = deg - cs; if (cl > CH) cl = CH;  // wave-uniform
    int e_v = (int)((unsigned long long)pr & 0xffffffffu);
    int s_v = (int)(pr >> 32);
    float xv[CH];
    // 1) FORCED 16-wide gather batch: volatile asm, scalar row base + v-offset.
    #pragma unroll
    for (int j = 0; j < CH; ++j) {
      int sj = __builtin_amdgcn_readlane(s_v, j);         // SGPR row id
      const float* pj = x + (size_t)(sj * OO + o) * CC;   // scalar address math
      asm volatile("global_load_dword %0, %1, %2"
                   : "=v"(xv[j]) : "v"(voff), "s"(pj));
    }
    asm volatile("s_waitcnt vmcnt(0)" ::: "memory");
    __builtin_amdgcn_sched_barrier(0);  // consumers must not hoist above the drain
    // 2) prefetch next chunk's pairs (in flight across the compute phase)
    int ns = cs + CH;
    if (ns < deg) {
      int ncl = deg - ns;
      pr = pairs[js + ns + min(lane16, ncl - 1)];
    }
    __builtin_amdgcn_sched_barrier(0);  // pin the prefetch issue before compute
    // 3) compute in 4-edge sub-blocks — no max/rescale chain, direct exp2
    #define SUB4(J0)                                                           \
    {                                                                          \
      float kv0 = kv_dot(kb, __builtin_amdgcn_readlane(e_v, (J0) + 0), obase, kw0, kw1, kw2, kw3); \
      float kv1 = kv_dot(kb, __builtin_amdgcn_readlane(e_v, (J0) + 1), obase, kw0, kw1, kw2, kw3); \
      float kv2 = kv_dot(kb, __builtin_amdgcn_readlane(e_v, (J0) + 2), obase, kw0, kw1, kw2, kw3); \
      float kv3 = kv_dot(kb, __builtin_amdgcn_readlane(e_v, (J0) + 3), obase, kw0, kw1, kw2, kw3); \
      float p0, p1, p2, p3;                                                    \
      red4(xv[(J0) + 0] * ubr, xv[(J0) + 1] * ubr,                             \
           xv[(J0) + 2] * ubr, xv[(J0) + 3] * ubr, p0, p1, p2, p3);            \
      float ev0 = ((J0) + 0 < cl) ? exp2_fast(p0) : 0.f;                       \
      float ev1 = ((J0) + 1 < cl) ? exp2_fast(p1) : 0.f;                       \
      float ev2 = ((J0) + 2 < cl) ? exp2_fast(p2) : 0.f;                       \
      float ev3 = ((J0) + 3 < cl) ? exp2_fast(p3) : 0.f;                       \
      S += (ev0 + ev1) + (ev2 + ev3);                                          \
      acc = fmaf(ev0 * kv0, xv[(J0) + 0], acc);                                \
      acc = fmaf(ev1 * kv1, xv[(J0) + 1], acc);                                \
      acc = fmaf(ev2 * kv2, xv[(J0) + 2], acc);                                \
      acc = fmaf(ev3 * kv3, xv[(J0) + 3], acc);                                \
    }
    SUB4(0)
    if (cl > 4)  SUB4(4)
    if (cl > 8)  SUB4(8)
    if (cl > 12) SUB4(12)
    #undef SUB4
  }

  // epsilon restored in the unshifted-logit domain: denom = S + 1e-6*2^(-base2)
  float invd = 1.0f / (S + 1e-6f * exp2_fast(-base2));
  x1[t] = acc * invd;
  __syncthreads();
  // fiber mix: out[n,p=o,c] = sum_oo x1[oo,c]*fk[o,oo,c] + bias[c]  (0.25 in fk)
  float s2s = 0.f;
  #pragma unroll
  for (int oo = 0; oo < OO; ++oo)
    s2s = fmaf(x1[oo * CC + c], fkg[o * (OO * CC) + oo * CC + c], s2s);
  out[(size_t)n * (OO * CC) + t] = s2s + bias[c];
}

extern "C" void kernel_launch(void* const* d_in, const int* in_sizes, int n_in,
                              void* d_out, int out_size, void* d_ws, size_t ws_size,
                              hipStream_t stream) {
  const float* x    = (const float*)d_in[0];
  const float* kb   = (const float*)d_in[1];
  const float* fkb  = (const float*)d_in[2];
  const int*   ei   = (const int*)d_in[3];
  const float* kW   = (const float*)d_in[4];
  const float* fkW  = (const float*)d_in[5];
  const float* keyW = (const float*)d_in[6];
  const float* keyB = (const float*)d_in[7];
  const float* qryW = (const float*)d_in[8];
  const float* qryB = (const float*)d_in[9];
  const float* bias = (const float*)d_in[10];
  float* out = (float*)d_out;

  const int NB = (NN + 255) / 256;  // 196 scan blocks

  float* wsf  = (float*)d_ws;
  float* Mt   = wsf;                          // 4096
  float* aVec = Mt + 4096;                    // 64
  float* bVec = aVec + 64;                    // 64
  float* c0   = bVec + 64;                    // 1 (+63 pad)
  float* fk   = c0 + 64;                      // 1024
  long long* pairs = (long long*)(fk + 1024); // EE * 8B (8B-aligned: 5312 floats before)
  int* counts    = (int*)(pairs + EE);        // 50000
  int* offsets   = counts + NN;               // 50001
  int* incl      = offsets + NN + 1;          // 50000
  int* bsum      = incl + NN;                 // NB
  int* bbase     = bsum + 256;                // NB

  hipMemsetAsync(counts, 0, (size_t)NN * sizeof(int), stream);

  prep_kernel<<<17, 256, 0, stream>>>(keyW, keyB, qryW, qryB, fkb, fkW, Mt, aVec, bVec, c0, fk);
  count_kernel<<<(EE + 255) / 256, 256, 0, stream>>>(ei, counts);
  scan1_kernel<<<NB, 256, 0, stream>>>(counts, incl, bsum, NN);
  scan2_kernel<<<1, 256, 0, stream>>>(bsum, bbase, NB);
  scan3_kernel<<<NB, 256, 0, stream>>>(counts, incl, bbase, offsets, NN);
  fill_kernel<<<(EE + 255) / 256, 256, 0, stream>>>(ei, offsets, counts, pairs);
  mega_kernel<<<NN, 256, 0, stream>>>(x, Mt, aVec, bVec, c0, kb, kW, offsets, pairs,
                                      fk, bias, out);
}

// Round 19
// 404.350 us; speedup vs baseline: 1.0847x; 1.0077x over previous
//
#include <hip/hip_runtime.h>
#include <math.h>

#define NN 50000
#define EE 800000
#define OO 4
#define CC 64
#define KDD 16
#define KEYDD 128
#define CH 8  // edges per pipelined chunk (ping-pong xvA/xvB = 16 VGPRs total)

typedef float v2f __attribute__((ext_vector_type(2)));

// Full-wave (64-lane) sum via DPP builtins (prologue + cleanup only)
__device__ __forceinline__ float wave_red_sum(float v) {
  int x;
  x = __builtin_amdgcn_update_dpp(0, __float_as_int(v), 0x111, 0xf, 0xf, false);
  v += __int_as_float(x);
  x = __builtin_amdgcn_update_dpp(0, __float_as_int(v), 0x112, 0xf, 0xf, false);
  v += __int_as_float(x);
  x = __builtin_amdgcn_update_dpp(0, __float_as_int(v), 0x114, 0xf, 0xf, false);
  v += __int_as_float(x);
  x = __builtin_amdgcn_update_dpp(0, __float_as_int(v), 0x118, 0xf, 0xf, false);
  v += __int_as_float(x);
  x = __builtin_amdgcn_update_dpp(0, __float_as_int(v), 0x142, 0xa, 0xf, false);
  v += __int_as_float(x);
  x = __builtin_amdgcn_update_dpp(0, __float_as_int(v), 0x143, 0xc, 0xf, false);
  v += __int_as_float(x);
  return __int_as_float(__builtin_amdgcn_readlane(__float_as_int(v), 63));
}

// bare v_exp_f32: D = 2^x  (softmax runs in log2 domain)
__device__ __forceinline__ float exp2_fast(float x) {
  float r;
  asm("v_exp_f32 %0, %1" : "=v"(r) : "v"(x));
  return r;
}

// Batched reduction of FOUR 64-lane vectors -> four wave-uniform sums.
// permlane32_swap folds pairs; one asm block of 10 v_add_f32_dpp with the two
// independent chains interleaved (covers DPP wait-states). Totals at lanes 31/63.
__device__ __forceinline__ void red4(float q0, float q1, float q2, float q3,
                                     float& p0, float& p1, float& p2, float& p3) {
  asm("s_nop 1\n\tv_permlane32_swap_b32 %0, %1" : "+v"(q0), "+v"(q1));
  float ra = q0 + q1;
  asm("s_nop 1\n\tv_permlane32_swap_b32 %0, %1" : "+v"(q2), "+v"(q3));
  float rb = q2 + q3;
  asm("s_nop 1\n\t"
      "v_add_f32_dpp %0, %0, %0 row_shr:1 row_mask:0xf bank_mask:0xf bound_ctrl:0\n\t"
      "v_add_f32_dpp %1, %1, %1 row_shr:1 row_mask:0xf bank_mask:0xf bound_ctrl:0\n\t"
      "v_add_f32_dpp %0, %0, %0 row_shr:2 row_mask:0xf bank_mask:0xf bound_ctrl:0\n\t"
      "v_add_f32_dpp %1, %1, %1 row_shr:2 row_mask:0xf bank_mask:0xf bound_ctrl:0\n\t"
      "v_add_f32_dpp %0, %0, %0 row_shr:4 row_mask:0xf bank_mask:0xf bound_ctrl:0\n\t"
      "v_add_f32_dpp %1, %1, %1 row_shr:4 row_mask:0xf bank_mask:0xf bound_ctrl:0\n\t"
      "v_add_f32_dpp %0, %0, %0 row_shr:8 row_mask:0xf bank_mask:0xf bound_ctrl:0\n\t"
      "v_add_f32_dpp %1, %1, %1 row_shr:8 row_mask:0xf bank_mask:0xf bound_ctrl:0\n\t"
      "v_add_f32_dpp %0, %0, %0 row_bcast:15 row_mask:0xa bank_mask:0xf bound_ctrl:0\n\t"
      "v_add_f32_dpp %1, %1, %1 row_bcast:15 row_mask:0xa bank_mask:0xf bound_ctrl:0\n\t"
      "s_nop 0"
      : "+v"(ra), "+v"(rb));
  p0 = __int_as_float(__builtin_amdgcn_readlane(__float_as_int(ra), 31));
  p1 = __int_as_float(__builtin_amdgcn_readlane(__float_as_int(ra), 63));
  p2 = __int_as_float(__builtin_amdgcn_readlane(__float_as_int(rb), 31));
  p3 = __int_as_float(__builtin_amdgcn_readlane(__float_as_int(rb), 63));
}

// P0 (blocks 0..15): Mt[c2*64+c1] = sum_k keyW[k,c1]*qryW[k,c2] (transposed).
// Block 16: aVec/bVec/c0/fk (fk pre-scaled by 0.25).
__global__ void prep_kernel(const float* __restrict__ keyW, const float* __restrict__ keyB,
                            const float* __restrict__ qryW, const float* __restrict__ qryB,
                            const float* __restrict__ fkb, const float* __restrict__ fkw,
                            float* __restrict__ Mt, float* __restrict__ aVec,
                            float* __restrict__ bVec, float* __restrict__ c0,
                            float* __restrict__ fk) {
  __shared__ float qw[KEYDD * CC];   // 32 KB
  __shared__ float kws[KEYDD * 4];   // 2 KB
  int t = threadIdx.x, b = blockIdx.x;
  if (b < 16) {
    for (int i = t; i < KEYDD * CC; i += 256) qw[i] = qryW[i];
    for (int i = t; i < KEYDD * 4; i += 256) {
      int k = i >> 2, c1l = i & 3;
      kws[i] = keyW[k * CC + b * 4 + c1l];
    }
    __syncthreads();
    int c1l = t >> 6, c2 = t & 63;
    float s = 0.f;
    #pragma unroll 8
    for (int k = 0; k < KEYDD; ++k)
      s = fmaf(kws[k * 4 + c1l], qw[k * CC + c2], s);
    Mt[c2 * CC + b * 4 + c1l] = s;
  } else {
    if (t < CC) {
      float sa = 0.f, sb = 0.f;
      for (int k = 0; k < KEYDD; ++k) {
        sa = fmaf(keyB[k], qryW[k * CC + t], sa);
        sb = fmaf(qryB[k], keyW[k * CC + t], sb);
      }
      aVec[t] = sa; bVec[t] = sb;
    }
    if (t == 0) {
      float s = 0.f;
      for (int k = 0; k < KEYDD; ++k) s = fmaf(keyB[k], qryB[k], s);
      c0[0] = s;
    }
    for (int idx = t; idx < OO * OO * CC; idx += 256) {
      int p = idx >> 8, rem = idx & 255;
      int o = rem >> 6, c = rem & 63;
      float s = 0.f;
      #pragma unroll
      for (int kd = 0; kd < KDD; ++kd)
        s = fmaf(fkb[(p * OO + o) * KDD + kd], fkw[c * KDD + kd], s);
      fk[idx] = 0.25f * s;  // fold the 1/O normalization here
    }
  }
}

// K2a: CSR degree counts
__global__ void count_kernel(const int* __restrict__ ei, int* __restrict__ counts) {
  int e = blockIdx.x * 256 + threadIdx.x;
  if (e < EE) atomicAdd(&counts[ei[EE + e]], 1);
}

// K2b: 3-dispatch parallel exclusive scan over counts[NN] -> offsets[NN+1]
__global__ void scan1_kernel(const int* __restrict__ counts, int* __restrict__ incl,
                             int* __restrict__ bsum, int n) {
  __shared__ int buf[256];
  int t = threadIdx.x;
  int i = blockIdx.x * 256 + t;
  int v = (i < n) ? counts[i] : 0;
  buf[t] = v;
  __syncthreads();
  for (int off = 1; off < 256; off <<= 1) {
    int a = buf[t];
    int b2 = (t >= off) ? buf[t - off] : 0;
    __syncthreads();
    buf[t] = a + b2;
    __syncthreads();
  }
  if (i < n) incl[i] = buf[t];
  if (t == 255) bsum[blockIdx.x] = buf[255];
}
__global__ void scan2_kernel(const int* __restrict__ bsum, int* __restrict__ bbase, int nb) {
  __shared__ int buf[256];
  int t = threadIdx.x;
  int v = (t < nb) ? bsum[t] : 0;
  buf[t] = v;
  __syncthreads();
  for (int off = 1; off < 256; off <<= 1) {
    int a = buf[t];
    int b2 = (t >= off) ? buf[t - off] : 0;
    __syncthreads();
    buf[t] = a + b2;
    __syncthreads();
  }
  if (t < nb) bbase[t] = buf[t] - v;  // exclusive
}
__global__ void scan3_kernel(const int* __restrict__ counts, const int* __restrict__ incl,
                             const int* __restrict__ bbase, int* __restrict__ offsets, int n) {
  int i = blockIdx.x * 256 + threadIdx.x;
  if (i < n) {
    int oi = bbase[blockIdx.x] + incl[i];
    offsets[i] = oi - counts[i];
    if (i == n - 1) offsets[n] = oi;
  }
}

// K2c: fill CSR as packed (src<<32 | eid) pairs; reuses counts as cursor.
__global__ void fill_kernel(const int* __restrict__ ei, const int* __restrict__ offsets,
                            int* __restrict__ counts, long long* __restrict__ pairs) {
  int e = blockIdx.x * 256 + threadIdx.x;
  if (e < EE) {
    int d = ei[EE + e];
    int r = atomicSub(&counts[d], 1) - 1;
    int pos = offsets[d] + r;
    pairs[pos] = ((long long)ei[e] << 32) | (unsigned)e;
  }
}

// kv = dot16(kb[ej, o, :], kW[c, :]) via PACKED f32 math: 8 v_pk_fma_f32
// + 1 pk_add + 1 add. ej is an SGPR -> wave-uniform s_load path.
__device__ __forceinline__ float kv_dot(const float* __restrict__ kb, int ej, int obase,
                                        float4 kw0, float4 kw1, float4 kw2, float4 kw3) {
  const float4* bp = reinterpret_cast<const float4*>(kb + ej * (OO * KDD) + obase);
  float4 b0 = bp[0], b1 = bp[1], b2 = bp[2], b3 = bp[3];
  v2f a0 = {0.f, 0.f}, a1 = {0.f, 0.f};
  #define P2(f4, i) (reinterpret_cast<const v2f*>(&(f4))[i])
  a0 = __builtin_elementwise_fma(P2(b0, 0), P2(kw0, 0), a0);
  a1 = __builtin_elementwise_fma(P2(b0, 1), P2(kw0, 1), a1);
  a0 = __builtin_elementwise_fma(P2(b1, 0), P2(kw1, 0), a0);
  a1 = __builtin_elementwise_fma(P2(b1, 1), P2(kw1, 1), a1);
  a0 = __builtin_elementwise_fma(P2(b2, 0), P2(kw2, 0), a0);
  a1 = __builtin_elementwise_fma(P2(b2, 1), P2(kw2, 1), a1);
  a0 = __builtin_elementwise_fma(P2(b3, 0), P2(kw3, 0), a0);
  a1 = __builtin_elementwise_fma(P2(b3, 1), P2(kw3, 1), a1);
  #undef P2
  v2f s = a0 + a1;
  return s.x + s.y;
}

// K3: MEGA — R14 frame + CH=8 CROSS-CHUNK GATHER PIPELINE, minimal state.
// Why this differs from every failed pipeline attempt:
//   R9  compiler-managed loads -> queue entanglement, occ collapse
//   R15 CH=16 ping-pong + idx rotation -> 64+ live regs, SPILL (2.2GB scratch)
//   R16 LDS DMA -> barrier re-coupling
// Here: ALL pairs for the node load ONCE 64-wide (deg<=64 for this input;
// never-taken scalar cleanup for deg>64), so there is NO per-chunk index
// dependency chain; pipeline state is only xvA[8]+xvB[8]=16 VGPRs. Per
// iteration: drain -> issue next chunk's 8 asm gathers -> compute current 8
// edges (~360cy VALU covers most of the 400-600cy gather latency, plus TLP).
// readlane uses runtime SGPR lane (cs+j) — legal, 1 s_min + v_readlane each.
// WRITE_SIZE is the spill tripwire: must stay 50MB.
__global__ __launch_bounds__(256, 4) void mega_kernel(
    const float* __restrict__ x, const float* __restrict__ Mt,
    const float* __restrict__ aVec, const float* __restrict__ bVec,
    const float* __restrict__ c0p, const float* __restrict__ kb,
    const float* __restrict__ kW, const int* __restrict__ offsets,
    const long long* __restrict__ pairs, const float* __restrict__ fkg,
    const float* __restrict__ bias, float* __restrict__ out) {
  __shared__ float x1[OO * CC];
  int n = blockIdx.x;
  int t = threadIdx.x;
  int o = __builtin_amdgcn_readfirstlane(t >> 6);
  int c = t & 63;
  const float scale2 = 0.12751541050862828f;  // (1/sqrt(128)) * log2(e)
  int js = offsets[n], je = offsets[n + 1];
  int deg = je - js;
  int dm1 = deg - 1;  // wave-uniform

  // whole-node pairs preload, 64-wide (in flight under the ub compute)
  long long prAll = 0;
  if (deg > 0) prAll = pairs[js + min(c, dm1)];

  // ub = (Mt^T xrow + bVec) * scale2 — scalar-pipe xrow, 4 split chains (R14)
  int rowoff = __builtin_amdgcn_readfirstlane((n * OO + o) * CC);
  const float* xrow = x + rowoff;
  float ub0 = 0.f, ub1 = 0.f, ub2 = 0.f, ub3 = 0.f;
  #pragma unroll
  for (int q = 0; q < 16; ++q) {
    ub0 = fmaf(Mt[(4 * q + 0) * CC + c], xrow[4 * q + 0], ub0);
    ub1 = fmaf(Mt[(4 * q + 1) * CC + c], xrow[4 * q + 1], ub1);
    ub2 = fmaf(Mt[(4 * q + 2) * CC + c], xrow[4 * q + 2], ub2);
    ub3 = fmaf(Mt[(4 * q + 3) * CC + c], xrow[4 * q + 3], ub3);
  }
  float ubr = (((ub0 + ub1) + (ub2 + ub3)) + bVec[c]) * scale2;
  float xown = xrow[c];  // per-lane read of own row (vector load)
  float base2 = (wave_red_sum(aVec[c] * xown) + c0p[0]) * scale2;

  const float4* kwp = reinterpret_cast<const float4*>(kW + c * KDD);
  float4 kw0 = kwp[0], kw1 = kwp[1], kw2 = kwp[2], kw3 = kwp[3];
  int obase = o * KDD;
  int voff = c << 2;  // per-lane byte offset into a row

  int e_all = (int)((unsigned long long)prAll & 0xffffffffu);
  int s_all = (int)(prAll >> 32);

  float S = 0.f, acc = 0.f;
  int degc = min(deg, 64);  // pipelined portion (deg>64 handled by cleanup)

  // issue one chunk's 8 gathers (volatile asm; runtime-SGPR readlane lane)
  #define GATHER(XV, CS)                                                       \
  {                                                                            \
    _Pragma("unroll")                                                          \
    for (int j = 0; j < CH; ++j) {                                             \
      int li = (CS) + j; li = (li < dm1) ? li : dm1;                           \
      int sj = __builtin_amdgcn_readlane(s_all, li);                           \
      const float* pj = x + (size_t)(sj * OO + o) * CC;                        \
      asm volatile("global_load_dword %0, %1, %2"                              \
                   : "=v"(XV[j]) : "v"(voff), "s"(pj));                        \
    }                                                                          \
  }
  #define SUB4(XV, CS, J0, CL)                                                 \
  {                                                                            \
    int la = (CS)+(J0)+0; la = (la < dm1) ? la : dm1;                          \
    int lb = (CS)+(J0)+1; lb = (lb < dm1) ? lb : dm1;                          \
    int lc2 = (CS)+(J0)+2; lc2 = (lc2 < dm1) ? lc2 : dm1;                      \
    int ld = (CS)+(J0)+3; ld = (ld < dm1) ? ld : dm1;                          \
    float kv0 = kv_dot(kb, __builtin_amdgcn_readlane(e_all, la), obase, kw0, kw1, kw2, kw3);  \
    float kv1 = kv_dot(kb, __builtin_amdgcn_readlane(e_all, lb), obase, kw0, kw1, kw2, kw3);  \
    float kv2 = kv_dot(kb, __builtin_amdgcn_readlane(e_all, lc2), obase, kw0, kw1, kw2, kw3); \
    float kv3 = kv_dot(kb, __builtin_amdgcn_readlane(e_all, ld), obase, kw0, kw1, kw2, kw3);  \
    float p0, p1, p2, p3;                                                      \
    red4(XV[(J0) + 0] * ubr, XV[(J0) + 1] * ubr,                               \
         XV[(J0) + 2] * ubr, XV[(J0) + 3] * ubr, p0, p1, p2, p3);              \
    float ev0 = ((J0) + 0 < (CL)) ? exp2_fast(p0) : 0.f;                       \
    float ev1 = ((J0) + 1 < (CL)) ? exp2_fast(p1) : 0.f;                       \
    float ev2 = ((J0) + 2 < (CL)) ? exp2_fast(p2) : 0.f;                       \
    float ev3 = ((J0) + 3 < (CL)) ? exp2_fast(p3) : 0.f;                       \
    S += (ev0 + ev1) + (ev2 + ev3);                                            \
    acc = fmaf(ev0 * kv0, XV[(J0) + 0], acc);                                  \
    acc = fmaf(ev1 * kv1, XV[(J0) + 1], acc);                                  \
    acc = fmaf(ev2 * kv2, XV[(J0) + 2], acc);                                  \
    acc = fmaf(ev3 * kv3, XV[(J0) + 3], acc);                                  \
  }
  #define COMPUTE(XV, CS, CL)                                                  \
    SUB4(XV, CS, 0, CL)                                                        \
    if ((CL) > 4) SUB4(XV, CS, 4, CL)

  if (degc > 0) {
    float xvA[CH], xvB[CH];
    GATHER(xvA, 0)
    int cs = 0;
    while (true) {
      // ---- chunk cs from xvA ----
      int cl = degc - cs; if (cl > CH) cl = CH;
      bool hasNext = (cs + CH) < degc;
      asm volatile("s_waitcnt vmcnt(0)" ::: "memory");  // xvA ready
      __builtin_amdgcn_sched_barrier(0);
      if (hasNext) GATHER(xvB, cs + CH)                 // next chunk in flight
      __builtin_amdgcn_sched_barrier(0);
      COMPUTE(xvA, cs, cl)
      if (!hasNext) break;
      cs += CH;
      // ---- chunk cs from xvB ----
      cl = degc - cs; if (cl > CH) cl = CH;
      hasNext = (cs + CH) < degc;
      asm volatile("s_waitcnt vmcnt(0)" ::: "memory");  // xvB ready
      __builtin_amdgcn_sched_barrier(0);
      if (hasNext) GATHER(xvA, cs + CH)
      __builtin_amdgcn_sched_barrier(0);
      COMPUTE(xvB, cs, cl)
      if (!hasNext) break;
      cs += CH;
    }
  }
  #undef COMPUTE
  #undef SUB4
  #undef GATHER

  // never-taken scalar cleanup for deg > 64 (correctness guard; max deg ~40)
  for (int eidx = 64; eidx < deg; ++eidx) {
    long long pp = pairs[js + eidx];
    int sid = __builtin_amdgcn_readfirstlane((int)(pp >> 32));
    int eid = __builtin_amdgcn_readfirstlane((int)((unsigned long long)pp & 0xffffffffu));
    float xe = x[(size_t)(sid * OO + o) * CC + c];
    float p = wave_red_sum(xe * ubr);
    float ev = exp2_fast(p);
    float kv = kv_dot(kb, eid, obase, kw0, kw1, kw2, kw3);
    S += ev;
    acc = fmaf(ev * kv, xe, acc);
  }

  // epsilon restored in the unshifted-logit domain: denom = S + 1e-6*2^(-base2)
  float invd = 1.0f / (S + 1e-6f * exp2_fast(-base2));
  x1[t] = acc * invd;
  __syncthreads();
  // fiber mix: out[n,p=o,c] = sum_oo x1[oo,c]*fk[o,oo,c] + bias[c]  (0.25 in fk)
  float s2s = 0.f;
  #pragma unroll
  for (int oo = 0; oo < OO; ++oo)
    s2s = fmaf(x1[oo * CC + c], fkg[o * (OO * CC) + oo * CC + c], s2s);
  out[(size_t)n * (OO * CC) + t] = s2s + bias[c];
}

extern "C" void kernel_launch(void* const* d_in, const int* in_sizes, int n_in,
                              void* d_out, int out_size, void* d_ws, size_t ws_size,
                              hipStream_t stream) {
  const float* x    = (const float*)d_in[0];
  const float* kb   = (const float*)d_in[1];
  const float* fkb  = (const float*)d_in[2];
  const int*   ei   = (const int*)d_in[3];
  const float* kW   = (const float*)d_in[4];
  const float* fkW  = (const float*)d_in[5];
  const float* keyW = (const float*)d_in[6];
  const float* keyB = (const float*)d_in[7];
  const float* qryW = (const float*)d_in[8];
  const float* qryB = (const float*)d_in[9];
  const float* bias = (const float*)d_in[10];
  float* out = (float*)d_out;

  const int NB = (NN + 255) / 256;  // 196 scan blocks

  float* wsf  = (float*)d_ws;
  float* Mt   = wsf;                          // 4096
  float* aVec = Mt + 4096;                    // 64
  float* bVec = aVec + 64;                    // 64
  float* c0   = bVec + 64;                    // 1 (+63 pad)
  float* fk   = c0 + 64;                      // 1024
  long long* pairs = (long long*)(fk + 1024); // EE * 8B (8B-aligned: 5312 floats before)
  int* counts    = (int*)(pairs + EE);        // 50000
  int* offsets   = counts + NN;               // 50001
  int* incl      = offsets + NN + 1;          // 50000
  int* bsum      = incl + NN;                 // NB
  int* bbase     = bsum + 256;                // NB

  hipMemsetAsync(counts, 0, (size_t)NN * sizeof(int), stream);

  prep_kernel<<<17, 256, 0, stream>>>(keyW, keyB, qryW, qryB, fkb, fkW, Mt, aVec, bVec, c0, fk);
  count_kernel<<<(EE + 255) / 256, 256, 0, stream>>>(ei, counts);
  scan1_kernel<<<NB, 256, 0, stream>>>(counts, incl, bsum, NN);
  scan2_kernel<<<1, 256, 0, stream>>>(bsum, bbase, NB);
  scan3_kernel<<<NB, 256, 0, stream>>>(counts, incl, bbase, offsets, NN);
  fill_kernel<<<(EE + 255) / 256, 256, 0, stream>>>(ei, offsets, counts, pairs);
  mega_kernel<<<NN, 256, 0, stream>>>(x, Mt, aVec, bVec, c0, kb, kW, offsets, pairs,
                                      fk, bias, out);
}

// Round 20
// 402.059 us; speedup vs baseline: 1.0908x; 1.0057x over previous
//
#include <hip/hip_runtime.h>
#include <math.h>

#define NN 50000
#define EE 800000
#define OO 4
#define CC 64
#define KDD 16
#define KEYDD 128
#define CH 8  // edges per pipelined chunk; 3 buffers -> 2 chunks in flight

typedef float v2f __attribute__((ext_vector_type(2)));

// Full-wave (64-lane) sum via DPP builtins (prologue + cleanup only)
__device__ __forceinline__ float wave_red_sum(float v) {
  int x;
  x = __builtin_amdgcn_update_dpp(0, __float_as_int(v), 0x111, 0xf, 0xf, false);
  v += __int_as_float(x);
  x = __builtin_amdgcn_update_dpp(0, __float_as_int(v), 0x112, 0xf, 0xf, false);
  v += __int_as_float(x);
  x = __builtin_amdgcn_update_dpp(0, __float_as_int(v), 0x114, 0xf, 0xf, false);
  v += __int_as_float(x);
  x = __builtin_amdgcn_update_dpp(0, __float_as_int(v), 0x118, 0xf, 0xf, false);
  v += __int_as_float(x);
  x = __builtin_amdgcn_update_dpp(0, __float_as_int(v), 0x142, 0xa, 0xf, false);
  v += __int_as_float(x);
  x = __builtin_amdgcn_update_dpp(0, __float_as_int(v), 0x143, 0xc, 0xf, false);
  v += __int_as_float(x);
  return __int_as_float(__builtin_amdgcn_readlane(__float_as_int(v), 63));
}

// bare v_exp_f32: D = 2^x  (softmax runs in log2 domain)
__device__ __forceinline__ float exp2_fast(float x) {
  float r;
  asm("v_exp_f32 %0, %1" : "=v"(r) : "v"(x));
  return r;
}

// Batched reduction of FOUR 64-lane vectors -> four wave-uniform sums.
// permlane32_swap folds pairs; one asm block of 10 v_add_f32_dpp with the two
// independent chains interleaved (covers DPP wait-states). Totals at lanes 31/63.
__device__ __forceinline__ void red4(float q0, float q1, float q2, float q3,
                                     float& p0, float& p1, float& p2, float& p3) {
  asm("s_nop 1\n\tv_permlane32_swap_b32 %0, %1" : "+v"(q0), "+v"(q1));
  float ra = q0 + q1;
  asm("s_nop 1\n\tv_permlane32_swap_b32 %0, %1" : "+v"(q2), "+v"(q3));
  float rb = q2 + q3;
  asm("s_nop 1\n\t"
      "v_add_f32_dpp %0, %0, %0 row_shr:1 row_mask:0xf bank_mask:0xf bound_ctrl:0\n\t"
      "v_add_f32_dpp %1, %1, %1 row_shr:1 row_mask:0xf bank_mask:0xf bound_ctrl:0\n\t"
      "v_add_f32_dpp %0, %0, %0 row_shr:2 row_mask:0xf bank_mask:0xf bound_ctrl:0\n\t"
      "v_add_f32_dpp %1, %1, %1 row_shr:2 row_mask:0xf bank_mask:0xf bound_ctrl:0\n\t"
      "v_add_f32_dpp %0, %0, %0 row_shr:4 row_mask:0xf bank_mask:0xf bound_ctrl:0\n\t"
      "v_add_f32_dpp %1, %1, %1 row_shr:4 row_mask:0xf bank_mask:0xf bound_ctrl:0\n\t"
      "v_add_f32_dpp %0, %0, %0 row_shr:8 row_mask:0xf bank_mask:0xf bound_ctrl:0\n\t"
      "v_add_f32_dpp %1, %1, %1 row_shr:8 row_mask:0xf bank_mask:0xf bound_ctrl:0\n\t"
      "v_add_f32_dpp %0, %0, %0 row_bcast:15 row_mask:0xa bank_mask:0xf bound_ctrl:0\n\t"
      "v_add_f32_dpp %1, %1, %1 row_bcast:15 row_mask:0xa bank_mask:0xf bound_ctrl:0\n\t"
      "s_nop 0"
      : "+v"(ra), "+v"(rb));
  p0 = __int_as_float(__builtin_amdgcn_readlane(__float_as_int(ra), 31));
  p1 = __int_as_float(__builtin_amdgcn_readlane(__float_as_int(ra), 63));
  p2 = __int_as_float(__builtin_amdgcn_readlane(__float_as_int(rb), 31));
  p3 = __int_as_float(__builtin_amdgcn_readlane(__float_as_int(rb), 63));
}

// P0 (blocks 0..15): Mt[c2*64+c1] = sum_k keyW[k,c1]*qryW[k,c2] (transposed).
// Block 16: aVec/bVec/c0/fk (fk pre-scaled by 0.25).
__global__ void prep_kernel(const float* __restrict__ keyW, const float* __restrict__ keyB,
                            const float* __restrict__ qryW, const float* __restrict__ qryB,
                            const float* __restrict__ fkb, const float* __restrict__ fkw,
                            float* __restrict__ Mt, float* __restrict__ aVec,
                            float* __restrict__ bVec, float* __restrict__ c0,
                            float* __restrict__ fk) {
  __shared__ float qw[KEYDD * CC];   // 32 KB
  __shared__ float kws[KEYDD * 4];   // 2 KB
  int t = threadIdx.x, b = blockIdx.x;
  if (b < 16) {
    for (int i = t; i < KEYDD * CC; i += 256) qw[i] = qryW[i];
    for (int i = t; i < KEYDD * 4; i += 256) {
      int k = i >> 2, c1l = i & 3;
      kws[i] = keyW[k * CC + b * 4 + c1l];
    }
    __syncthreads();
    int c1l = t >> 6, c2 = t & 63;
    float s = 0.f;
    #pragma unroll 8
    for (int k = 0; k < KEYDD; ++k)
      s = fmaf(kws[k * 4 + c1l], qw[k * CC + c2], s);
    Mt[c2 * CC + b * 4 + c1l] = s;
  } else {
    if (t < CC) {
      float sa = 0.f, sb = 0.f;
      for (int k = 0; k < KEYDD; ++k) {
        sa = fmaf(keyB[k], qryW[k * CC + t], sa);
        sb = fmaf(qryB[k], keyW[k * CC + t], sb);
      }
      aVec[t] = sa; bVec[t] = sb;
    }
    if (t == 0) {
      float s = 0.f;
      for (int k = 0; k < KEYDD; ++k) s = fmaf(keyB[k], qryB[k], s);
      c0[0] = s;
    }
    for (int idx = t; idx < OO * OO * CC; idx += 256) {
      int p = idx >> 8, rem = idx & 255;
      int o = rem >> 6, c = rem & 63;
      float s = 0.f;
      #pragma unroll
      for (int kd = 0; kd < KDD; ++kd)
        s = fmaf(fkb[(p * OO + o) * KDD + kd], fkw[c * KDD + kd], s);
      fk[idx] = 0.25f * s;  // fold the 1/O normalization here
    }
  }
}

// K2a: CSR degree counts
__global__ void count_kernel(const int* __restrict__ ei, int* __restrict__ counts) {
  int e = blockIdx.x * 256 + threadIdx.x;
  if (e < EE) atomicAdd(&counts[ei[EE + e]], 1);
}

// K2b: 3-dispatch parallel exclusive scan over counts[NN] -> offsets[NN+1]
__global__ void scan1_kernel(const int* __restrict__ counts, int* __restrict__ incl,
                             int* __restrict__ bsum, int n) {
  __shared__ int buf[256];
  int t = threadIdx.x;
  int i = blockIdx.x * 256 + t;
  int v = (i < n) ? counts[i] : 0;
  buf[t] = v;
  __syncthreads();
  for (int off = 1; off < 256; off <<= 1) {
    int a = buf[t];
    int b2 = (t >= off) ? buf[t - off] : 0;
    __syncthreads();
    buf[t] = a + b2;
    __syncthreads();
  }
  if (i < n) incl[i] = buf[t];
  if (t == 255) bsum[blockIdx.x] = buf[255];
}
__global__ void scan2_kernel(const int* __restrict__ bsum, int* __restrict__ bbase, int nb) {
  __shared__ int buf[256];
  int t = threadIdx.x;
  int v = (t < nb) ? bsum[t] : 0;
  buf[t] = v;
  __syncthreads();
  for (int off = 1; off < 256; off <<= 1) {
    int a = buf[t];
    int b2 = (t >= off) ? buf[t - off] : 0;
    __syncthreads();
    buf[t] = a + b2;
    __syncthreads();
  }
  if (t < nb) bbase[t] = buf[t] - v;  // exclusive
}
__global__ void scan3_kernel(const int* __restrict__ counts, const int* __restrict__ incl,
                             const int* __restrict__ bbase, int* __restrict__ offsets, int n) {
  int i = blockIdx.x * 256 + threadIdx.x;
  if (i < n) {
    int oi = bbase[blockIdx.x] + incl[i];
    offsets[i] = oi - counts[i];
    if (i == n - 1) offsets[n] = oi;
  }
}

// K2c: fill CSR as packed (src<<32 | eid) pairs; reuses counts as cursor.
__global__ void fill_kernel(const int* __restrict__ ei, const int* __restrict__ offsets,
                            int* __restrict__ counts, long long* __restrict__ pairs) {
  int e = blockIdx.x * 256 + threadIdx.x;
  if (e < EE) {
    int d = ei[EE + e];
    int r = atomicSub(&counts[d], 1) - 1;
    int pos = offsets[d] + r;
    pairs[pos] = ((long long)ei[e] << 32) | (unsigned)e;
  }
}

// kv = dot16(kb[ej, o, :], kW[c, :]) via PACKED f32 math: 8 v_pk_fma_f32
// + 1 pk_add + 1 add. ej is an SGPR -> wave-uniform s_load path (lgkmcnt,
// does NOT interact with the manual vmcnt pipeline).
__device__ __forceinline__ float kv_dot(const float* __restrict__ kb, int ej, int obase,
                                        float4 kw0, float4 kw1, float4 kw2, float4 kw3) {
  const float4* bp = reinterpret_cast<const float4*>(kb + ej * (OO * KDD) + obase);
  float4 b0 = bp[0], b1 = bp[1], b2 = bp[2], b3 = bp[3];
  v2f a0 = {0.f, 0.f}, a1 = {0.f, 0.f};
  #define P2(f4, i) (reinterpret_cast<const v2f*>(&(f4))[i])
  a0 = __builtin_elementwise_fma(P2(b0, 0), P2(kw0, 0), a0);
  a1 = __builtin_elementwise_fma(P2(b0, 1), P2(kw0, 1), a1);
  a0 = __builtin_elementwise_fma(P2(b1, 0), P2(kw1, 0), a0);
  a1 = __builtin_elementwise_fma(P2(b1, 1), P2(kw1, 1), a1);
  a0 = __builtin_elementwise_fma(P2(b2, 0), P2(kw2, 0), a0);
  a1 = __builtin_elementwise_fma(P2(b2, 1), P2(kw2, 1), a1);
  a0 = __builtin_elementwise_fma(P2(b3, 0), P2(kw3, 0), a0);
  a1 = __builtin_elementwise_fma(P2(b3, 1), P2(kw3, 1), a1);
  #undef P2
  v2f s = a0 + a1;
  return s.x + s.y;
}

// K3: MEGA — R19 frame + 2-DEEP COUNTED-vmcnt PIPELINE (T3/T4 pattern:
// "never drain vmcnt to 0 in the main loop"). Three 8-float buffers rotate
// A->B->C; invariant entering chunk i: chunks i and i+1 in flight (16 loads);
// s_waitcnt vmcnt(8) retires exactly chunk i, chunk i+1 stays airborne with a
// full chunk of compute (~720cy) still ahead of its own wait. Correctness of
// the counted queue: an explicit vmcnt(0) flush AFTER the prologue removes all
// compiler VMEM (Mt/xown/pairs loads) from the queue; inside the loop the only
// vmcnt ops are these volatile-asm gathers (kb = s_load/lgkm; stores after).
// Pipeline state = 24 VGPRs (R15's spill came from 64+; tripwire: WRITE_SIZE).
__global__ __launch_bounds__(256, 4) void mega_kernel(
    const float* __restrict__ x, const float* __restrict__ Mt,
    const float* __restrict__ aVec, const float* __restrict__ bVec,
    const float* __restrict__ c0p, const float* __restrict__ kb,
    const float* __restrict__ kW, const int* __restrict__ offsets,
    const long long* __restrict__ pairs, const float* __restrict__ fkg,
    const float* __restrict__ bias, float* __restrict__ out) {
  __shared__ float x1[OO * CC];
  int n = blockIdx.x;
  int t = threadIdx.x;
  int o = __builtin_amdgcn_readfirstlane(t >> 6);
  int c = t & 63;
  const float scale2 = 0.12751541050862828f;  // (1/sqrt(128)) * log2(e)
  int js = offsets[n], je = offsets[n + 1];
  int deg = je - js;
  int dm1 = deg - 1;  // wave-uniform

  // whole-node pairs preload, 64-wide (in flight under the ub compute)
  long long prAll = 0;
  if (deg > 0) prAll = pairs[js + min(c, dm1)];

  // ub = (Mt^T xrow + bVec) * scale2 — scalar-pipe xrow, 4 split chains (R14)
  int rowoff = __builtin_amdgcn_readfirstlane((n * OO + o) * CC);
  const float* xrow = x + rowoff;
  float ub0 = 0.f, ub1 = 0.f, ub2 = 0.f, ub3 = 0.f;
  #pragma unroll
  for (int q = 0; q < 16; ++q) {
    ub0 = fmaf(Mt[(4 * q + 0) * CC + c], xrow[4 * q + 0], ub0);
    ub1 = fmaf(Mt[(4 * q + 1) * CC + c], xrow[4 * q + 1], ub1);
    ub2 = fmaf(Mt[(4 * q + 2) * CC + c], xrow[4 * q + 2], ub2);
    ub3 = fmaf(Mt[(4 * q + 3) * CC + c], xrow[4 * q + 3], ub3);
  }
  float ubr = (((ub0 + ub1) + (ub2 + ub3)) + bVec[c]) * scale2;
  float xown = xrow[c];  // per-lane read of own row (vector load)
  float base2 = (wave_red_sum(aVec[c] * xown) + c0p[0]) * scale2;

  const float4* kwp = reinterpret_cast<const float4*>(kW + c * KDD);
  float4 kw0 = kwp[0], kw1 = kwp[1], kw2 = kwp[2], kw3 = kwp[3];
  int obase = o * KDD;
  int voff = c << 2;  // per-lane byte offset into a row

  int e_all = (int)((unsigned long long)prAll & 0xffffffffu);
  int s_all = (int)(prAll >> 32);

  float S = 0.f, acc = 0.f;
  int degc = min(deg, 64);  // pipelined portion (deg>64 handled by cleanup)

  #define GATHER(XV, CS)                                                       \
  {                                                                            \
    _Pragma("unroll")                                                          \
    for (int j = 0; j < CH; ++j) {                                             \
      int li = (CS) + j; li = (li < dm1) ? li : dm1;                           \
      int sj = __builtin_amdgcn_readlane(s_all, li);                           \
      const float* pj = x + (size_t)(sj * OO + o) * CC;                        \
      asm volatile("global_load_dword %0, %1, %2"                              \
                   : "=v"(XV[j]) : "v"(voff), "s"(pj));                        \
    }                                                                          \
  }
  #define WAITK(HASN)                                                          \
    if (HASN) { asm volatile("s_waitcnt vmcnt(8)" ::: "memory"); }             \
    else      { asm volatile("s_waitcnt vmcnt(0)" ::: "memory"); }             \
    __builtin_amdgcn_sched_barrier(0);
  #define SUB4(XV, CS, J0, CL)                                                 \
  {                                                                            \
    int la = (CS)+(J0)+0; la = (la < dm1) ? la : dm1;                          \
    int lb = (CS)+(J0)+1; lb = (lb < dm1) ? lb : dm1;                          \
    int lc2 = (CS)+(J0)+2; lc2 = (lc2 < dm1) ? lc2 : dm1;                      \
    int ld = (CS)+(J0)+3; ld = (ld < dm1) ? ld : dm1;                          \
    float kv0 = kv_dot(kb, __builtin_amdgcn_readlane(e_all, la), obase, kw0, kw1, kw2, kw3);  \
    float kv1 = kv_dot(kb, __builtin_amdgcn_readlane(e_all, lb), obase, kw0, kw1, kw2, kw3);  \
    float kv2 = kv_dot(kb, __builtin_amdgcn_readlane(e_all, lc2), obase, kw0, kw1, kw2, kw3); \
    float kv3 = kv_dot(kb, __builtin_amdgcn_readlane(e_all, ld), obase, kw0, kw1, kw2, kw3);  \
    float p0, p1, p2, p3;                                                      \
    red4(XV[(J0) + 0] * ubr, XV[(J0) + 1] * ubr,                               \
         XV[(J0) + 2] * ubr, XV[(J0) + 3] * ubr, p0, p1, p2, p3);              \
    float ev0 = ((J0) + 0 < (CL)) ? exp2_fast(p0) : 0.f;                       \
    float ev1 = ((J0) + 1 < (CL)) ? exp2_fast(p1) : 0.f;                       \
    float ev2 = ((J0) + 2 < (CL)) ? exp2_fast(p2) : 0.f;                       \
    float ev3 = ((J0) + 3 < (CL)) ? exp2_fast(p3) : 0.f;                       \
    S += (ev0 + ev1) + (ev2 + ev3);                                            \
    acc = fmaf(ev0 * kv0, XV[(J0) + 0], acc);                                  \
    acc = fmaf(ev1 * kv1, XV[(J0) + 1], acc);                                  \
    acc = fmaf(ev2 * kv2, XV[(J0) + 2], acc);                                  \
    acc = fmaf(ev3 * kv3, XV[(J0) + 3], acc);                                  \
  }
  #define COMPUTE(XV, CS, CL)                                                  \
    SUB4(XV, CS, 0, CL)                                                        \
    if ((CL) > 4) SUB4(XV, CS, 4, CL)

  if (degc > 0) {
    float xvA[CH], xvB[CH], xvC[CH];
    // flush ALL compiler VMEM from the queue; from here on, only asm gathers.
    asm volatile("s_waitcnt vmcnt(0)" ::: "memory");
    __builtin_amdgcn_sched_barrier(0);
    GATHER(xvA, 0)
    if (CH < degc) GATHER(xvB, CH)
    int cs = 0;
    while (true) {
      // ---- stage A: chunk cs from xvA; issue cs+16 -> xvC ----
      int cl = degc - cs; if (cl > CH) cl = CH;
      bool hasN1 = (cs + CH) < degc;
      WAITK(hasN1)                                   // retire chunk cs only
      if (cs + 2 * CH < degc) GATHER(xvC, cs + 2 * CH)
      __builtin_amdgcn_sched_barrier(0);
      COMPUTE(xvA, cs, cl)
      if (!hasN1) break;
      cs += CH;
      // ---- stage B: chunk cs from xvB; issue cs+16 -> xvA ----
      cl = degc - cs; if (cl > CH) cl = CH;
      hasN1 = (cs + CH) < degc;
      WAITK(hasN1)
      if (cs + 2 * CH < degc) GATHER(xvA, cs + 2 * CH)
      __builtin_amdgcn_sched_barrier(0);
      COMPUTE(xvB, cs, cl)
      if (!hasN1) break;
      cs += CH;
      // ---- stage C: chunk cs from xvC; issue cs+16 -> xvB ----
      cl = degc - cs; if (cl > CH) cl = CH;
      hasN1 = (cs + CH) < degc;
      WAITK(hasN1)
      if (cs + 2 * CH < degc) GATHER(xvB, cs + 2 * CH)
      __builtin_amdgcn_sched_barrier(0);
      COMPUTE(xvC, cs, cl)
      if (!hasN1) break;
      cs += CH;
    }
  }
  #undef COMPUTE
  #undef SUB4
  #undef WAITK
  #undef GATHER

  // never-taken scalar cleanup for deg > 64 (correctness guard; max deg ~40)
  for (int eidx = 64; eidx < deg; ++eidx) {
    long long pp = pairs[js + eidx];
    int sid = __builtin_amdgcn_readfirstlane((int)(pp >> 32));
    int eid = __builtin_amdgcn_readfirstlane((int)((unsigned long long)pp & 0xffffffffu));
    float xe = x[(size_t)(sid * OO + o) * CC + c];
    float p = wave_red_sum(xe * ubr);
    float ev = exp2_fast(p);
    float kv = kv_dot(kb, eid, obase, kw0, kw1, kw2, kw3);
    S += ev;
    acc = fmaf(ev * kv, xe, acc);
  }

  // epsilon restored in the unshifted-logit domain: denom = S + 1e-6*2^(-base2)
  float invd = 1.0f / (S + 1e-6f * exp2_fast(-base2));
  x1[t] = acc * invd;
  __syncthreads();
  // fiber mix: out[n,p=o,c] = sum_oo x1[oo,c]*fk[o,oo,c] + bias[c]  (0.25 in fk)
  float s2s = 0.f;
  #pragma unroll
  for (int oo = 0; oo < OO; ++oo)
    s2s = fmaf(x1[oo * CC + c], fkg[o * (OO * CC) + oo * CC + c], s2s);
  out[(size_t)n * (OO * CC) + t] = s2s + bias[c];
}

extern "C" void kernel_launch(void* const* d_in, const int* in_sizes, int n_in,
                              void* d_out, int out_size, void* d_ws, size_t ws_size,
                              hipStream_t stream) {
  const float* x    = (const float*)d_in[0];
  const float* kb   = (const float*)d_in[1];
  const float* fkb  = (const float*)d_in[2];
  const int*   ei   = (const int*)d_in[3];
  const float* kW   = (const float*)d_in[4];
  const float* fkW  = (const float*)d_in[5];
  const float* keyW = (const float*)d_in[6];
  const float* keyB = (const float*)d_in[7];
  const float* qryW = (const float*)d_in[8];
  const float* qryB = (const float*)d_in[9];
  const float* bias = (const float*)d_in[10];
  float* out = (float*)d_out;

  const int NB = (NN + 255) / 256;  // 196 scan blocks

  float* wsf  = (float*)d_ws;
  float* Mt   = wsf;                          // 4096
  float* aVec = Mt + 4096;                    // 64
  float* bVec = aVec + 64;                    // 64
  float* c0   = bVec + 64;                    // 1 (+63 pad)
  float* fk   = c0 + 64;                      // 1024
  long long* pairs = (long long*)(fk + 1024); // EE * 8B (8B-aligned: 5312 floats before)
  int* counts    = (int*)(pairs + EE);        // 50000
  int* offsets   = counts + NN;               // 50001
  int* incl      = offsets + NN + 1;          // 50000
  int* bsum      = incl + NN;                 // NB
  int* bbase     = bsum + 256;                // NB

  hipMemsetAsync(counts, 0, (size_t)NN * sizeof(int), stream);

  prep_kernel<<<17, 256, 0, stream>>>(keyW, keyB, qryW, qryB, fkb, fkW, Mt, aVec, bVec, c0, fk);
  count_kernel<<<(EE + 255) / 256, 256, 0, stream>>>(ei, counts);
  scan1_kernel<<<NB, 256, 0, stream>>>(counts, incl, bsum, NN);
  scan2_kernel<<<1, 256, 0, stream>>>(bsum, bbase, NB);
  scan3_kernel<<<NB, 256, 0, stream>>>(counts, incl, bbase, offsets, NN);
  fill_kernel<<<(EE + 255) / 256, 256, 0, stream>>>(ei, offsets, counts, pairs);
  mega_kernel<<<NN, 256, 0, stream>>>(x, Mt, aVec, bVec, c0, kb, kW, offsets, pairs,
                                      fk, bias, out);
}